// Round 15
// baseline (119.357 us; speedup 1.0000x reference)
//
#include <hip/hip_runtime.h>
#include <hip/hip_bf16.h>
#include <stdint.h>

typedef __attribute__((ext_vector_type(8))) short short8;
typedef __attribute__((ext_vector_type(4))) float f32x4;

static __device__ __forceinline__ unsigned short f2bf(float f) {
  union { float f; unsigned u; } v; v.f = f;
  return (unsigned short)((v.u + 0x7fffu + ((v.u >> 16) & 1u)) >> 16);
}
static __device__ __forceinline__ float bf2f(unsigned short h) {
  union { unsigned u; float f; } v; v.u = ((unsigned)h) << 16;
  return v.f;
}
// packed f32x2 -> bf16x2 (RNE), gfx950 (no builtin; T12 recipe)
static __device__ __forceinline__ unsigned cvt_pk_bf16(float lo, float hi) {
  unsigned r;
  asm("v_cvt_pk_bf16_f32 %0, %1, %2" : "=v"(r) : "v"(lo), "v"(hi));
  return r;
}

// async global->LDS, 16B per lane (guide §5; LDS dest = wave-uniform base + lane*16)
#define GLL16(gp, lp) __builtin_amdgcn_global_load_lds(                        \
    (__attribute__((address_space(1))) void*)(uintptr_t)(gp),                  \
    (__attribute__((address_space(3))) void*)(lp), 16, 0, 0)

// element-index XOR swizzle for 64-elem (128B) bf16 rows: spreads the
// 128B-stride column reads across 8 bank-granules (T2; involution).
#define SWZ(r, e) ((e) ^ (((r) & 7) << 3))

// ---------------- fused cast f32 -> bf16 for x, w_qkv, w_out ----------------
__global__ void cast3(const float* __restrict__ a, unsigned short* __restrict__ oa, int na4,
                      const float* __restrict__ b, unsigned short* __restrict__ ob, int nb4,
                      const float* __restrict__ c, unsigned short* __restrict__ oc, int nc4) {
  int i = blockIdx.x * 256 + threadIdx.x;
  const float* src;
  unsigned short* dst;
  int j = i;
  if (j < na4) { src = a; dst = oa; }
  else if ((j -= na4) < nb4) { src = b; dst = ob; }
  else { j -= nb4; if (j >= nc4) return; src = c; dst = oc; }
  const float4 v = reinterpret_cast<const float4*>(src)[j];
  ushort4 o;
  o.x = f2bf(v.x); o.y = f2bf(v.y); o.z = f2bf(v.z); o.w = f2bf(v.w);
  reinterpret_cast<ushort4*>(dst)[j] = o;
}

// ---------------- GEMM1 + fused RoPE/layout epilogue (LDS-staged) -----------
// K-loop: 2-phase dbuf (issue next-tile gll16 BEFORE compute, 1 barrier/step).
// Epilogue: q/k RoPE + [t][c] stage; v [c][t] swizzled (all coalesced out).
__global__ __launch_bounds__(256) void gemm_qkv(
    const unsigned short* __restrict__ A, const unsigned short* __restrict__ B,
    unsigned short* __restrict__ qb, unsigned short* __restrict__ kb,
    unsigned short* __restrict__ vt) {
  constexpr int K = 1024;
  __shared__ unsigned short smem[128 * 136];  // K-loop: 32KB dbuf; epilogue: 34KB stage
  const int tid = threadIdx.x;
  const int lane = tid & 63;
  const int w = tid >> 6;
  const int wr = w >> 1, wc = w & 1;
  const int l15 = lane & 15, lg = lane >> 4;
  const size_t bm = (size_t)blockIdx.x * 128;
  const size_t bn = (size_t)blockIdx.y * 128;
  const unsigned short* Ab = A + bm * K;
  const unsigned short* Bb = B + bn * K;
  f32x4 acc[4][4];
#pragma unroll
  for (int m = 0; m < 4; ++m)
#pragma unroll
    for (int n = 0; n < 4; ++n) acc[m][n] = (f32x4){0.f, 0.f, 0.f, 0.f};

#pragma unroll
  for (int p = 0; p < 2; ++p) {
    const int flat = p * 256 + tid;
    const int row = flat >> 2;
    const int c8 = (flat & 3) << 3;
    GLL16(Ab + (size_t)row * K + c8, smem + flat * 8);
    GLL16(Bb + (size_t)row * K + c8, smem + 8192 + flat * 8);
  }
  __syncthreads();
  int cur = 0;
  for (int k0 = 0; k0 < K; k0 += 32) {
    if (k0 + 32 < K) {  // issue next tile BEFORE compute (latency hides)
      const int nb = cur ^ 1;
#pragma unroll
      for (int p = 0; p < 2; ++p) {
        const int flat = p * 256 + tid;
        const int row = flat >> 2;
        const int c8 = (flat & 3) << 3;
        GLL16(Ab + (size_t)row * K + k0 + 32 + c8, smem + nb * 4096 + flat * 8);
        GLL16(Bb + (size_t)row * K + k0 + 32 + c8, smem + 8192 + nb * 4096 + flat * 8);
      }
    }
    const unsigned short* Asc = smem + cur * 4096;
    const unsigned short* Bsc = smem + 8192 + cur * 4096;
    short8 af[4], bf[4];
#pragma unroll
    for (int m = 0; m < 4; ++m)
      af[m] = *reinterpret_cast<const short8*>(Asc + ((wr * 64 + m * 16 + l15) * 32 + lg * 8));
#pragma unroll
    for (int n = 0; n < 4; ++n)
      bf[n] = *reinterpret_cast<const short8*>(Bsc + ((wc * 64 + n * 16 + l15) * 32 + lg * 8));
#pragma unroll
    for (int m = 0; m < 4; ++m)
#pragma unroll
      for (int n = 0; n < 4; ++n)
        acc[m][n] = __builtin_amdgcn_mfma_f32_16x16x32_bf16(af[m], bf[n], acc[m][n], 0, 0, 0);
    __syncthreads();  // vmcnt(0): next tile staged; lgkm: buf[cur] reads done
    cur ^= 1;
  }

  // smem is now the staging tile (final barrier above covers the handoff)
  const int sec = (int)(bn >> 10);                 // 0=q 1=k 2=v (block-uniform)
  const int hbase = (int)((bn & 1023) >> 6);
  if (sec < 2) {
    // ---- q/k: RoPE in regs, stage [t][c] as packed dwords ----
    unsigned* st32 = reinterpret_cast<unsigned*>(smem);
    const float scl = sec ? 1.0f : (0.125f * 1.44269504089f);  // q: 1/sqrt(D)*log2e
    const bool even = (l15 & 1) == 0;
#pragma unroll
    for (int n = 0; n < 4; ++n) {
      const int c = wc * 64 + n * 16 + l15;        // local col 0..127
      const int jj = (c & 63) >> 1;
      const int h = hbase + (c >> 6);
      const float freq = __expf(-(float)jj * (9.210340371976184f / 32.0f));  // ln(1e4)/32
      float sn, cs;
      __sincosf((float)h * freq, &sn, &cs);
#pragma unroll
      for (int m = 0; m < 4; ++m)
#pragma unroll
        for (int r = 0; r < 4; ++r) {
          const float v = acc[m][n][r];
          const float p = __shfl_xor(v, 1);        // partner of the RoPE pair
          if (even) {                              // even lane emits both outputs
            const float o0 = (v * cs - p * sn) * scl;
            const float o1 = (v * sn + p * cs) * scl;
            const int tl = wr * 64 + lg * 4 + m * 16 + r;
            st32[tl * 68 + (c >> 1)] = cvt_pk_bf16(o0, o1);
          }
        }
    }
    __syncthreads();
    unsigned short* dst = sec ? kb : qb;
#pragma unroll
    for (int p8 = 0; p8 < 8; ++p8) {
      const int id = p8 * 256 + tid;               // 2048 ushort8-chunks
      const int tlc = id >> 4, cch = id & 15;
      const short8 val = *reinterpret_cast<const short8*>(smem + tlc * 136 + cch * 8);
      const int trow = (int)bm + tlc;
      const int b = trow >> 11, t = trow & 2047;
      const int h = hbase + (cch >> 3), d0 = (cch & 7) * 8;
      *reinterpret_cast<short8*>(dst + (((size_t)(b * 16 + h) * 2048 + t) << 6) + d0) = val;
    }
  } else {
    // ---- v: stage [c][t] with 4-elem-granule swizzle, coalesced d-major out ----
#pragma unroll
    for (int n = 0; n < 4; ++n) {
      const int c = wc * 64 + n * 16 + l15;
      const int x = (c & 7) << 2;
#pragma unroll
      for (int m = 0; m < 4; ++m) {
        const int gt = wr * 16 + lg + m * 4;       // t-granule index (4 t each)
        ushort4 pk;
        pk.x = f2bf(acc[m][n][0]); pk.y = f2bf(acc[m][n][1]);
        pk.z = f2bf(acc[m][n][2]); pk.w = f2bf(acc[m][n][3]);
        *reinterpret_cast<ushort4*>(smem + c * 136 + ((gt ^ x) << 2)) = pk;
      }
    }
    __syncthreads();
#pragma unroll
    for (int p8 = 0; p8 < 8; ++p8) {
      const int id = p8 * 256 + tid;
      const int cl = id >> 4, tch = id & 15;
      const int x = (cl & 7) << 2;
      const short8 val =
          *reinterpret_cast<const short8*>(smem + cl * 136 + (((tch * 2) ^ x) << 2));
      const int col = (int)(bn & 1023) + cl;
      const int h = col >> 6, d = col & 63;
      const int trow = (int)bm + tch * 8;
      const int b = trow >> 11, t = trow & 2047;
      *reinterpret_cast<short8*>(vt + ((size_t)((b * 16 + h) * 64 + d)) * 2048 + t) = val;
    }
  }
}

// ---------------- NT GEMM (output fp32): C = ctx @ w_out^T ------------------
// 2-phase dbuf K-loop.
__global__ __launch_bounds__(256) void gemm_nt_f32(
    const unsigned short* __restrict__ A, const unsigned short* __restrict__ B,
    float* __restrict__ Cout, int M, int N, int K) {
  __shared__ unsigned short smem[4 * 4096];  // As 0/4096, Bs 8192/12288
  const int tid = threadIdx.x;
  const int lane = tid & 63;
  const int w = tid >> 6;
  const int wr = w >> 1, wc = w & 1;
  const int l15 = lane & 15, lg = lane >> 4;
  const size_t bm = (size_t)blockIdx.x * 128;
  const size_t bn = (size_t)blockIdx.y * 128;
  const unsigned short* Ab = A + bm * K;
  const unsigned short* Bb = B + bn * K;
  f32x4 acc[4][4];
#pragma unroll
  for (int m = 0; m < 4; ++m)
#pragma unroll
    for (int n = 0; n < 4; ++n) acc[m][n] = (f32x4){0.f, 0.f, 0.f, 0.f};

#pragma unroll
  for (int p = 0; p < 2; ++p) {
    const int flat = p * 256 + tid;
    const int row = flat >> 2;
    const int c8 = (flat & 3) << 3;
    GLL16(Ab + (size_t)row * K + c8, smem + flat * 8);
    GLL16(Bb + (size_t)row * K + c8, smem + 8192 + flat * 8);
  }
  __syncthreads();
  int cur = 0;
  for (int k0 = 0; k0 < K; k0 += 32) {
    if (k0 + 32 < K) {
      const int nb = cur ^ 1;
#pragma unroll
      for (int p = 0; p < 2; ++p) {
        const int flat = p * 256 + tid;
        const int row = flat >> 2;
        const int c8 = (flat & 3) << 3;
        GLL16(Ab + (size_t)row * K + k0 + 32 + c8, smem + nb * 4096 + flat * 8);
        GLL16(Bb + (size_t)row * K + k0 + 32 + c8, smem + 8192 + nb * 4096 + flat * 8);
      }
    }
    const unsigned short* Asc = smem + cur * 4096;
    const unsigned short* Bsc = smem + 8192 + cur * 4096;
    short8 af[4], bf[4];
#pragma unroll
    for (int m = 0; m < 4; ++m)
      af[m] = *reinterpret_cast<const short8*>(Asc + ((wr * 64 + m * 16 + l15) * 32 + lg * 8));
#pragma unroll
    for (int n = 0; n < 4; ++n)
      bf[n] = *reinterpret_cast<const short8*>(Bsc + ((wc * 64 + n * 16 + l15) * 32 + lg * 8));
#pragma unroll
    for (int m = 0; m < 4; ++m)
#pragma unroll
      for (int n = 0; n < 4; ++n)
        acc[m][n] = __builtin_amdgcn_mfma_f32_16x16x32_bf16(af[m], bf[n], acc[m][n], 0, 0, 0);
    __syncthreads();
    cur ^= 1;
  }
  const size_t row0 = bm + wr * 64 + lg * 4;
  const size_t col0 = bn + wc * 64 + l15;
#pragma unroll
  for (int m = 0; m < 4; ++m)
#pragma unroll
    for (int n = 0; n < 4; ++n)
#pragma unroll
      for (int r = 0; r < 4; ++r)
        Cout[(row0 + m * 16 + r) * N + col0 + n * 16] = acc[m][n][r];
}

// ---------------- flash attention: 4 waves x 32 q-rows (QBLK=128) -----------
// R14 analysis: 8-wave version was LDS-read-bound (each wave re-reads full
// K/V tile for only 16 q-rows -> 176KB LDS reads/block-tile). 4 waves x 32 q
// halves that (each wave's 16 K/V frag reads feed 32 MFMA, 2 q-subtiles).
// grid (16, B*H), 256 thr. T1 bh-remap kept (FETCH 65->12MB in R14).
// px in [0,8) pairs q-tiles (px,15-px), sx splits s-range: 17 units/block.
// mrun init -1e5 (NOT -1e30): fully-masked wave-tile must give p=0, not p=1.
__global__ __launch_bounds__(256) void attn_kernel(
    const unsigned short* __restrict__ qb, const unsigned short* __restrict__ kb,
    const unsigned short* __restrict__ vt, unsigned short* __restrict__ partO,
    float2* __restrict__ partML) {
  __shared__ unsigned short Ks[2][64 * 64];  // [s][d], swizzled
  __shared__ unsigned short Vs[2][64 * 64];  // [d][s], swizzled
  __shared__ unsigned short Ps[4][32 * 64];  // per-wave P [32q][64s], swizzled
  const int tid = threadIdx.x;
  const int lane = tid & 63;
  const int w = tid >> 6;                    // 0..3
  const int l15 = lane & 15, lg = lane >> 4;
  // XCD-aware bijective remap: fid in [0,512)
  const int fid = (int)(blockIdx.y * 16 + blockIdx.x);
  const int j = fid >> 3;
  const int bh = ((fid & 7) << 2) + (j >> 4);           // 4 bh per XCD
  const int inner = j & 15;
  const int sx = inner & 1, px = inner >> 1;            // px in [0,8)
  unsigned short* Pw = &Ps[w][0];

  // staging base pointers: 256 thr x 2 passes stage one 64x64 tile per matrix
  const unsigned short* kg[2];
  const unsigned short* vg[2];
#pragma unroll
  for (int p = 0; p < 2; ++p) {
    const int flat = p * 256 + tid;
    const int row = flat >> 3;
    const int gc8 = SWZ(row, (flat & 7) << 3);
    kg[p] = kb + ((size_t)bh * 2048 + row) * 64 + gc8;   // +4096/tile
    vg[p] = vt + ((size_t)bh * 64 + row) * 2048 + gc8;   // +64/tile
  }

  int cur = 0;
#pragma unroll 1
  for (int mem = 0; mem < 2; ++mem) {
    const int qt = mem ? (15 - px) : px;     // 128-row q-tile index, each once
    const int nt = 2 * qt + 2;               // s-tiles in causal range
    const int mid = nt >> 1;
    const int sb = sx ? mid : 0;
    const int se = sx ? nt : mid;
    const int nh = se - sb;                  // = qt+1 for both halves
    const int qw = qt * 128 + w * 32;        // wave's first q row (32 rows)
    const unsigned short* Qp = qb + ((size_t)bh * 2048 + qw) * 64;
    short8 qf[2][2];
#pragma unroll
    for (int qs = 0; qs < 2; ++qs) {
      qf[qs][0] = *reinterpret_cast<const short8*>(Qp + (size_t)(qs * 16 + l15) * 64 + lg * 8);
      qf[qs][1] = *reinterpret_cast<const short8*>(Qp + (size_t)(qs * 16 + l15) * 64 + 32 + lg * 8);
    }
    float mrun[2] = {-1e5f, -1e5f}, lrun[2] = {0.f, 0.f};
    f32x4 o[2][4];
#pragma unroll
    for (int qs = 0; qs < 2; ++qs)
#pragma unroll
      for (int dt = 0; dt < 4; ++dt) o[qs][dt] = (f32x4){0.f, 0.f, 0.f, 0.f};

    if (nh > 0) {  // block-uniform
#pragma unroll
      for (int p = 0; p < 2; ++p) {
        const int flat = p * 256 + tid;
        GLL16(kg[p] + (size_t)sb * 4096, &Ks[cur][flat * 8]);
        GLL16(vg[p] + (size_t)sb * 64, &Vs[cur][flat * 8]);
      }
      __syncthreads();

#pragma unroll 1
      for (int it = 0; it < nh; ++it) {
        const int ti = sb + it;
        const int s0 = ti * 64;
        if (it + 1 < nh) {  // issue next tile BEFORE compute
#pragma unroll
          for (int p = 0; p < 2; ++p) {
            const int flat = p * 256 + tid;
            GLL16(kg[p] + (size_t)(ti + 1) * 4096, &Ks[cur ^ 1][flat * 8]);
            GLL16(vg[p] + (size_t)(ti + 1) * 64, &Vs[cur ^ 1][flat * 8]);
          }
        }
        const unsigned short* Kc = &Ks[cur][0];
        const unsigned short* Vc = &Vs[cur][0];
        // swapped QK^T: sc[qs][st] col(l15)=q-local, row(lg*4+r)=s-local
        f32x4 sc[2][4];
        __builtin_amdgcn_s_setprio(1);
#pragma unroll
        for (int st = 0; st < 4; ++st) {
          const int kr = st * 16 + l15;
          const short8 kf0 = *reinterpret_cast<const short8*>(Kc + kr * 64 + SWZ(kr, lg * 8));
          const short8 kf1 = *reinterpret_cast<const short8*>(Kc + kr * 64 + SWZ(kr, 32 + lg * 8));
#pragma unroll
          for (int qs = 0; qs < 2; ++qs) {
            f32x4 z = (f32x4){0.f, 0.f, 0.f, 0.f};
            z = __builtin_amdgcn_mfma_f32_16x16x32_bf16(kf0, qf[qs][0], z, 0, 0, 0);
            z = __builtin_amdgcn_mfma_f32_16x16x32_bf16(kf1, qf[qs][1], z, 0, 0, 0);
            sc[qs][st] = z;
          }
        }
        __builtin_amdgcn_s_setprio(0);
        // causal mask: q = qw + qs*16 + l15, s = s0 + st*16 + lg*4 + r
#pragma unroll
        for (int qs = 0; qs < 2; ++qs) {
          if (s0 + 63 > qw + qs * 16) {
            const int sbase = s0 + lg * 4 - (qw + qs * 16) - l15;
#pragma unroll
            for (int st = 0; st < 4; ++st)
#pragma unroll
              for (int r = 0; r < 4; ++r)
                if (sbase + st * 16 + r > 0) sc[qs][st][r] = -1e30f;
          }
        }
#pragma unroll
        for (int qs = 0; qs < 2; ++qs) {
          float tmax = sc[qs][0][0];
#pragma unroll
          for (int st = 0; st < 4; ++st)
#pragma unroll
            for (int r = 0; r < 4; ++r) tmax = fmaxf(tmax, sc[qs][st][r]);
          tmax = fmaxf(tmax, __shfl_xor(tmax, 16));
          tmax = fmaxf(tmax, __shfl_xor(tmax, 32));
          // T13 defer-max
          if (__any(tmax > mrun[qs] + 8.f)) {
            const float mn = fmaxf(mrun[qs], tmax);
            const float c = exp2f(mrun[qs] - mn);
            mrun[qs] = mn;
            lrun[qs] *= c;
#pragma unroll
            for (int r = 0; r < 4; ++r) {
              const float cq = __shfl(c, lg * 4 + r);
              o[qs][0][r] *= cq; o[qs][1][r] *= cq;
              o[qs][2][r] *= cq; o[qs][3][r] *= cq;
            }
          }
          float psum = 0.f;
#pragma unroll
          for (int st = 0; st < 4; ++st) {
            const float p0 = exp2f(sc[qs][st][0] - mrun[qs]);
            const float p1 = exp2f(sc[qs][st][1] - mrun[qs]);
            const float p2 = exp2f(sc[qs][st][2] - mrun[qs]);
            const float p3 = exp2f(sc[qs][st][3] - mrun[qs]);
            psum += (p0 + p1) + (p2 + p3);
            const unsigned lo = cvt_pk_bf16(p0, p1);
            const unsigned hi = cvt_pk_bf16(p2, p3);
            const int off = qs * 1024 + l15 * 64 + SWZ(l15, st * 16 + lg * 4);
            *reinterpret_cast<uint2*>(Pw + off) = make_uint2(lo, hi);
          }
          psum += __shfl_xor(psum, 16);
          psum += __shfl_xor(psum, 32);
          lrun[qs] += psum;
        }
        // PV: O[32q][64d] += P[32q][64s] * V[64s][64d]; vf shared across qs
        __builtin_amdgcn_s_setprio(1);
#pragma unroll
        for (int sc2 = 0; sc2 < 2; ++sc2) {
          const short8 pf0 = *reinterpret_cast<const short8*>(
              Pw + l15 * 64 + SWZ(l15, sc2 * 32 + lg * 8));
          const short8 pf1 = *reinterpret_cast<const short8*>(
              Pw + 1024 + l15 * 64 + SWZ(l15, sc2 * 32 + lg * 8));
#pragma unroll
          for (int dt = 0; dt < 4; ++dt) {
            const int vr = dt * 16 + l15;
            const short8 vf =
                *reinterpret_cast<const short8*>(Vc + vr * 64 + SWZ(vr, sc2 * 32 + lg * 8));
            o[0][dt] = __builtin_amdgcn_mfma_f32_16x16x32_bf16(pf0, vf, o[0][dt], 0, 0, 0);
            o[1][dt] = __builtin_amdgcn_mfma_f32_16x16x32_bf16(pf1, vf, o[1][dt], 0, 0, 0);
          }
        }
        __builtin_amdgcn_s_setprio(0);
        __syncthreads();  // implicit vmcnt(0): next tile staged; buf[cur] free
        cur ^= 1;
      }
    }
    // unnormalized partial write: partO[sx][bh*2048 + t][d], ml for lg==0
#pragma unroll
    for (int qs = 0; qs < 2; ++qs) {
#pragma unroll
      for (int r = 0; r < 4; ++r) {
        const int t = qw + qs * 16 + lg * 4 + r;
        const size_t base = ((size_t)sx * 65536 + (size_t)bh * 2048 + t) * 64;
#pragma unroll
        for (int dt = 0; dt < 4; ++dt) partO[base + dt * 16 + l15] = f2bf(o[qs][dt][r]);
      }
      if (lg == 0)
        partML[sx * 65536 + bh * 2048 + qw + qs * 16 + l15] =
            make_float2(mrun[qs], lrun[qs]);
    }
  }
}

// ---------------- combine the two s-halves -> ctx bf16 ----------------------
__global__ __launch_bounds__(256) void attn_combine(
    const unsigned short* __restrict__ partO, const float2* __restrict__ partML,
    unsigned short* __restrict__ ctx) {
  const int id = blockIdx.x * 256 + threadIdx.x;
  const int R = id >> 3;
  const int d8 = (id & 7) << 3;
  const float2 ml0 = partML[R];
  const float2 ml1 = partML[65536 + R];
  const float M = fmaxf(ml0.x, ml1.x);
  const float w0 = exp2f(ml0.x - M), w1 = exp2f(ml1.x - M);
  const float inv = __builtin_amdgcn_rcpf(ml0.y * w0 + ml1.y * w1);
  const short8 a = *reinterpret_cast<const short8*>(partO + ((size_t)R * 64 + d8));
  const short8 c = *reinterpret_cast<const short8*>(partO + ((size_t)(65536 + R) * 64 + d8));
  const int bh = R >> 11, t = R & 2047;
  const int b = bh >> 4, h = bh & 15;
  short8 outv;
#pragma unroll
  for (int e = 0; e < 8; ++e)
    outv[e] = (short)f2bf((bf2f((unsigned short)a[e]) * w0 +
                           bf2f((unsigned short)c[e]) * w1) * inv);
  *reinterpret_cast<short8*>(ctx + ((size_t)(b * 2048 + t) * 1024 + h * 64 + d8)) = outv;
}

// ---------------- launch ----------------------------------------------------
extern "C" void kernel_launch(void* const* d_in, const int* in_sizes, int n_in,
                              void* d_out, int out_size, void* d_ws, size_t ws_size,
                              hipStream_t stream) {
  const float* x = (const float*)d_in[0];
  const float* w_qkv = (const float*)d_in[1];
  const float* w_out = (const float*)d_in[2];
  // cache_k/cache_v/start_pos unused: start_pos=0, cache starts zero and is not returned.
  char* ws = (char*)d_ws;
  unsigned short* xb    = (unsigned short*)(ws);                       // 8 MiB
  unsigned short* wqkvb = (unsigned short*)(ws + (8ull  << 20));       // 6 MiB
  unsigned short* woutb = (unsigned short*)(ws + (14ull << 20));       // 2 MiB
  unsigned short* partO = (unsigned short*)(ws + (16ull << 20));       // 16 MiB
  float2* partML        = (float2*)(ws + (32ull << 20));               // 1 MiB
  unsigned short* q_buf = (unsigned short*)(ws + (40ull << 20));       // 8 MiB
  unsigned short* k_buf = (unsigned short*)(ws + (48ull << 20));       // 8 MiB
  unsigned short* vt    = (unsigned short*)(ws + (56ull << 20));       // 8 MiB
  unsigned short* ctxb  = (unsigned short*)(ws + (64ull << 20));       // 8 MiB (total 72)

  cast3<<<8192, 256, 0, stream>>>(x, xb, 1048576, w_qkv, wqkvb, 786432,
                                  w_out, woutb, 262144);
  gemm_qkv<<<dim3(32, 24), 256, 0, stream>>>(xb, wqkvb, q_buf, k_buf, vt);
  attn_kernel<<<dim3(16, 32), 256, 0, stream>>>(q_buf, k_buf, vt, partO, partML);
  attn_combine<<<2048, 256, 0, stream>>>(partO, partML, ctxb);
  gemm_nt_f32<<<dim3(32, 8), 256, 0, stream>>>(ctxb, woutb, (float*)d_out, 4096, 1024, 1024);
}

// Round 16
// 112.025 us; speedup vs baseline: 1.0654x; 1.0654x over previous
//
#include <hip/hip_runtime.h>
#include <hip/hip_bf16.h>
#include <stdint.h>

typedef __attribute__((ext_vector_type(8))) short short8;
typedef __attribute__((ext_vector_type(4))) float f32x4;

static __device__ __forceinline__ unsigned short f2bf(float f) {
  union { float f; unsigned u; } v; v.f = f;
  return (unsigned short)((v.u + 0x7fffu + ((v.u >> 16) & 1u)) >> 16);
}
static __device__ __forceinline__ float bf2f(unsigned short h) {
  union { unsigned u; float f; } v; v.u = ((unsigned)h) << 16;
  return v.f;
}
// packed f32x2 -> bf16x2 (RNE), gfx950 (no builtin; T12 recipe)
static __device__ __forceinline__ unsigned cvt_pk_bf16(float lo, float hi) {
  unsigned r;
  asm("v_cvt_pk_bf16_f32 %0, %1, %2" : "=v"(r) : "v"(lo), "v"(hi));
  return r;
}

// async global->LDS, 16B per lane (guide §5; LDS dest = wave-uniform base + lane*16)
#define GLL16(gp, lp) __builtin_amdgcn_global_load_lds(                        \
    (__attribute__((address_space(1))) void*)(uintptr_t)(gp),                  \
    (__attribute__((address_space(3))) void*)(lp), 16, 0, 0)

// element-index XOR swizzle for 64-elem (128B) bf16 rows: spreads the
// 128B-stride column reads across 8 bank-granules (T2; involution).
#define SWZ(r, e) ((e) ^ (((r) & 7) << 3))

// ---------------- fused cast f32 -> bf16 for x, w_qkv, w_out ----------------
__global__ void cast3(const float* __restrict__ a, unsigned short* __restrict__ oa, int na4,
                      const float* __restrict__ b, unsigned short* __restrict__ ob, int nb4,
                      const float* __restrict__ c, unsigned short* __restrict__ oc, int nc4) {
  int i = blockIdx.x * 256 + threadIdx.x;
  const float* src;
  unsigned short* dst;
  int j = i;
  if (j < na4) { src = a; dst = oa; }
  else if ((j -= na4) < nb4) { src = b; dst = ob; }
  else { j -= nb4; if (j >= nc4) return; src = c; dst = oc; }
  const float4 v = reinterpret_cast<const float4*>(src)[j];
  ushort4 o;
  o.x = f2bf(v.x); o.y = f2bf(v.y); o.z = f2bf(v.z); o.w = f2bf(v.w);
  reinterpret_cast<ushort4*>(dst)[j] = o;
}

// ---------------- GEMM1 + fused RoPE/layout epilogue (LDS-staged) -----------
// K-loop: 2-phase dbuf (issue next-tile gll16 BEFORE compute, 1 barrier/step).
// Epilogue: q/k RoPE + [t][c] stage; v [c][t] swizzled (all coalesced out).
__global__ __launch_bounds__(256) void gemm_qkv(
    const unsigned short* __restrict__ A, const unsigned short* __restrict__ B,
    unsigned short* __restrict__ qb, unsigned short* __restrict__ kb,
    unsigned short* __restrict__ vt) {
  constexpr int K = 1024;
  __shared__ unsigned short smem[128 * 136];  // K-loop: 32KB dbuf; epilogue: 34KB stage
  const int tid = threadIdx.x;
  const int lane = tid & 63;
  const int w = tid >> 6;
  const int wr = w >> 1, wc = w & 1;
  const int l15 = lane & 15, lg = lane >> 4;
  const size_t bm = (size_t)blockIdx.x * 128;
  const size_t bn = (size_t)blockIdx.y * 128;
  const unsigned short* Ab = A + bm * K;
  const unsigned short* Bb = B + bn * K;
  f32x4 acc[4][4];
#pragma unroll
  for (int m = 0; m < 4; ++m)
#pragma unroll
    for (int n = 0; n < 4; ++n) acc[m][n] = (f32x4){0.f, 0.f, 0.f, 0.f};

#pragma unroll
  for (int p = 0; p < 2; ++p) {
    const int flat = p * 256 + tid;
    const int row = flat >> 2;
    const int c8 = (flat & 3) << 3;
    GLL16(Ab + (size_t)row * K + c8, smem + flat * 8);
    GLL16(Bb + (size_t)row * K + c8, smem + 8192 + flat * 8);
  }
  __syncthreads();
  int cur = 0;
  for (int k0 = 0; k0 < K; k0 += 32) {
    if (k0 + 32 < K) {  // issue next tile BEFORE compute (latency hides)
      const int nb = cur ^ 1;
#pragma unroll
      for (int p = 0; p < 2; ++p) {
        const int flat = p * 256 + tid;
        const int row = flat >> 2;
        const int c8 = (flat & 3) << 3;
        GLL16(Ab + (size_t)row * K + k0 + 32 + c8, smem + nb * 4096 + flat * 8);
        GLL16(Bb + (size_t)row * K + k0 + 32 + c8, smem + 8192 + nb * 4096 + flat * 8);
      }
    }
    const unsigned short* Asc = smem + cur * 4096;
    const unsigned short* Bsc = smem + 8192 + cur * 4096;
    short8 af[4], bf[4];
#pragma unroll
    for (int m = 0; m < 4; ++m)
      af[m] = *reinterpret_cast<const short8*>(Asc + ((wr * 64 + m * 16 + l15) * 32 + lg * 8));
#pragma unroll
    for (int n = 0; n < 4; ++n)
      bf[n] = *reinterpret_cast<const short8*>(Bsc + ((wc * 64 + n * 16 + l15) * 32 + lg * 8));
#pragma unroll
    for (int m = 0; m < 4; ++m)
#pragma unroll
      for (int n = 0; n < 4; ++n)
        acc[m][n] = __builtin_amdgcn_mfma_f32_16x16x32_bf16(af[m], bf[n], acc[m][n], 0, 0, 0);
    __syncthreads();  // vmcnt(0): next tile staged; lgkm: buf[cur] reads done
    cur ^= 1;
  }

  // smem is now the staging tile (final barrier above covers the handoff)
  const int sec = (int)(bn >> 10);                 // 0=q 1=k 2=v (block-uniform)
  const int hbase = (int)((bn & 1023) >> 6);
  if (sec < 2) {
    // ---- q/k: RoPE in regs, stage [t][c] as packed dwords ----
    unsigned* st32 = reinterpret_cast<unsigned*>(smem);
    const float scl = sec ? 1.0f : (0.125f * 1.44269504089f);  // q: 1/sqrt(D)*log2e
    const bool even = (l15 & 1) == 0;
#pragma unroll
    for (int n = 0; n < 4; ++n) {
      const int c = wc * 64 + n * 16 + l15;        // local col 0..127
      const int jj = (c & 63) >> 1;
      const int h = hbase + (c >> 6);
      const float freq = __expf(-(float)jj * (9.210340371976184f / 32.0f));  // ln(1e4)/32
      float sn, cs;
      __sincosf((float)h * freq, &sn, &cs);
#pragma unroll
      for (int m = 0; m < 4; ++m)
#pragma unroll
        for (int r = 0; r < 4; ++r) {
          const float v = acc[m][n][r];
          const float p = __shfl_xor(v, 1);        // partner of the RoPE pair
          if (even) {                              // even lane emits both outputs
            const float o0 = (v * cs - p * sn) * scl;
            const float o1 = (v * sn + p * cs) * scl;
            const int tl = wr * 64 + lg * 4 + m * 16 + r;
            st32[tl * 68 + (c >> 1)] = cvt_pk_bf16(o0, o1);
          }
        }
    }
    __syncthreads();
    unsigned short* dst = sec ? kb : qb;
#pragma unroll
    for (int p8 = 0; p8 < 8; ++p8) {
      const int id = p8 * 256 + tid;               // 2048 ushort8-chunks
      const int tlc = id >> 4, cch = id & 15;
      const short8 val = *reinterpret_cast<const short8*>(smem + tlc * 136 + cch * 8);
      const int trow = (int)bm + tlc;
      const int b = trow >> 11, t = trow & 2047;
      const int h = hbase + (cch >> 3), d0 = (cch & 7) * 8;
      *reinterpret_cast<short8*>(dst + (((size_t)(b * 16 + h) * 2048 + t) << 6) + d0) = val;
    }
  } else {
    // ---- v: stage [c][t] with 4-elem-granule swizzle, coalesced d-major out ----
#pragma unroll
    for (int n = 0; n < 4; ++n) {
      const int c = wc * 64 + n * 16 + l15;
      const int x = (c & 7) << 2;
#pragma unroll
      for (int m = 0; m < 4; ++m) {
        const int gt = wr * 16 + lg + m * 4;       // t-granule index (4 t each)
        ushort4 pk;
        pk.x = f2bf(acc[m][n][0]); pk.y = f2bf(acc[m][n][1]);
        pk.z = f2bf(acc[m][n][2]); pk.w = f2bf(acc[m][n][3]);
        *reinterpret_cast<ushort4*>(smem + c * 136 + ((gt ^ x) << 2)) = pk;
      }
    }
    __syncthreads();
#pragma unroll
    for (int p8 = 0; p8 < 8; ++p8) {
      const int id = p8 * 256 + tid;
      const int cl = id >> 4, tch = id & 15;
      const int x = (cl & 7) << 2;
      const short8 val =
          *reinterpret_cast<const short8*>(smem + cl * 136 + (((tch * 2) ^ x) << 2));
      const int col = (int)(bn & 1023) + cl;
      const int h = col >> 6, d = col & 63;
      const int trow = (int)bm + tch * 8;
      const int b = trow >> 11, t = trow & 2047;
      *reinterpret_cast<short8*>(vt + ((size_t)((b * 16 + h) * 64 + d)) * 2048 + t) = val;
    }
  }
}

// ---------------- NT GEMM (output fp32): C = ctx @ w_out^T ------------------
// 2-phase dbuf K-loop.
__global__ __launch_bounds__(256) void gemm_nt_f32(
    const unsigned short* __restrict__ A, const unsigned short* __restrict__ B,
    float* __restrict__ Cout, int M, int N, int K) {
  __shared__ unsigned short smem[4 * 4096];  // As 0/4096, Bs 8192/12288
  const int tid = threadIdx.x;
  const int lane = tid & 63;
  const int w = tid >> 6;
  const int wr = w >> 1, wc = w & 1;
  const int l15 = lane & 15, lg = lane >> 4;
  const size_t bm = (size_t)blockIdx.x * 128;
  const size_t bn = (size_t)blockIdx.y * 128;
  const unsigned short* Ab = A + bm * K;
  const unsigned short* Bb = B + bn * K;
  f32x4 acc[4][4];
#pragma unroll
  for (int m = 0; m < 4; ++m)
#pragma unroll
    for (int n = 0; n < 4; ++n) acc[m][n] = (f32x4){0.f, 0.f, 0.f, 0.f};

#pragma unroll
  for (int p = 0; p < 2; ++p) {
    const int flat = p * 256 + tid;
    const int row = flat >> 2;
    const int c8 = (flat & 3) << 3;
    GLL16(Ab + (size_t)row * K + c8, smem + flat * 8);
    GLL16(Bb + (size_t)row * K + c8, smem + 8192 + flat * 8);
  }
  __syncthreads();
  int cur = 0;
  for (int k0 = 0; k0 < K; k0 += 32) {
    if (k0 + 32 < K) {
      const int nb = cur ^ 1;
#pragma unroll
      for (int p = 0; p < 2; ++p) {
        const int flat = p * 256 + tid;
        const int row = flat >> 2;
        const int c8 = (flat & 3) << 3;
        GLL16(Ab + (size_t)row * K + k0 + 32 + c8, smem + nb * 4096 + flat * 8);
        GLL16(Bb + (size_t)row * K + k0 + 32 + c8, smem + 8192 + nb * 4096 + flat * 8);
      }
    }
    const unsigned short* Asc = smem + cur * 4096;
    const unsigned short* Bsc = smem + 8192 + cur * 4096;
    short8 af[4], bf[4];
#pragma unroll
    for (int m = 0; m < 4; ++m)
      af[m] = *reinterpret_cast<const short8*>(Asc + ((wr * 64 + m * 16 + l15) * 32 + lg * 8));
#pragma unroll
    for (int n = 0; n < 4; ++n)
      bf[n] = *reinterpret_cast<const short8*>(Bsc + ((wc * 64 + n * 16 + l15) * 32 + lg * 8));
#pragma unroll
    for (int m = 0; m < 4; ++m)
#pragma unroll
      for (int n = 0; n < 4; ++n)
        acc[m][n] = __builtin_amdgcn_mfma_f32_16x16x32_bf16(af[m], bf[n], acc[m][n], 0, 0, 0);
    __syncthreads();
    cur ^= 1;
  }
  const size_t row0 = bm + wr * 64 + lg * 4;
  const size_t col0 = bn + wc * 64 + l15;
#pragma unroll
  for (int m = 0; m < 4; ++m)
#pragma unroll
    for (int n = 0; n < 4; ++n)
#pragma unroll
      for (int r = 0; r < 4; ++r)
        Cout[(row0 + m * 16 + r) * N + col0 + n * 16] = acc[m][n][r];
}

// ---------------- flash attention, causal, QBLK=128 8-wave + s-split --------
// R14 form restored (R15's 4-wave x 32q regressed: occupancy 32->18%, serial
// softmax chains exposed at 2 waves/SIMD; LDS-read saving didn't compensate).
// grid (16, B*H), 512 thr. T1 bh-remap: fid -> xcd=fid&7 owns bh in
// [4*xcd, 4*xcd+4) -> per-XCD K/V footprint 2MB <= 4MB L2 (FETCH 65->12MB).
// px in [0,8) pairs q-tiles (px,15-px), sx splits s-range: 17 units/block.
// mrun init -1e5 (NOT -1e30): fully-masked wave-tile must give p=0, not p=1.
__global__ __launch_bounds__(512, 2) void attn_kernel(
    const unsigned short* __restrict__ qb, const unsigned short* __restrict__ kb,
    const unsigned short* __restrict__ vt, unsigned short* __restrict__ partO,
    float2* __restrict__ partML) {
  __shared__ unsigned short Ks[2][64 * 64];  // [s][d], swizzled
  __shared__ unsigned short Vs[2][64 * 64];  // [d][s], swizzled
  __shared__ unsigned short Ps[8][16 * 64];  // per-wave P [q][s], swizzled
  const int tid = threadIdx.x;
  const int lane = tid & 63;
  const int w = tid >> 6;                    // 0..7
  const int l15 = lane & 15, lg = lane >> 4;
  // XCD-aware bijective remap: fid in [0,512)
  const int fid = (int)(blockIdx.y * 16 + blockIdx.x);
  const int j = fid >> 3;
  const int bh = ((fid & 7) << 2) + (j >> 4);           // 4 bh per XCD
  const int inner = j & 15;
  const int sx = inner & 1, px = inner >> 1;            // px in [0,8)
  unsigned short* Pw = &Ps[w][0];

  // staging base pointers (512 threads stage one 64x64 tile per buffer)
  const int srow = tid >> 3;
  const int gc8 = SWZ(srow, (tid & 7) << 3);
  const unsigned short* kg = kb + ((size_t)bh * 2048 + srow) * 64 + gc8;   // +4096/tile
  const unsigned short* vg = vt + ((size_t)bh * 64 + srow) * 2048 + gc8;   // +64/tile

  int cur = 0;
#pragma unroll 1
  for (int mem = 0; mem < 2; ++mem) {
    const int qt = mem ? (15 - px) : px;     // 128-row q-tile index, each once
    const int nt = 2 * qt + 2;               // s-tiles in causal range
    const int mid = nt >> 1;
    const int sb = sx ? mid : 0;
    const int se = sx ? nt : mid;
    const int nh = se - sb;                  // = qt+1 for both halves
    const int qw = qt * 128 + w * 16;
    const unsigned short* Qp = qb + ((size_t)bh * 2048 + qw) * 64;
    const short8 qf0 = *reinterpret_cast<const short8*>(Qp + (size_t)l15 * 64 + lg * 8);
    const short8 qf1 = *reinterpret_cast<const short8*>(Qp + (size_t)l15 * 64 + 32 + lg * 8);
    float mrun = -1e5f, lrun = 0.f;          // per-lane state for q-row qw+l15
    f32x4 o[4];
#pragma unroll
    for (int dt = 0; dt < 4; ++dt) o[dt] = (f32x4){0.f, 0.f, 0.f, 0.f};

    if (nh > 0) {  // block-uniform
      GLL16(kg + (size_t)sb * 4096, &Ks[cur][tid * 8]);
      GLL16(vg + (size_t)sb * 64, &Vs[cur][tid * 8]);
      __syncthreads();

#pragma unroll 1
      for (int it = 0; it < nh; ++it) {
        const int ti = sb + it;
        const int s0 = ti * 64;
        if (it + 1 < nh) {  // issue next tile BEFORE compute
          GLL16(kg + (size_t)(ti + 1) * 4096, &Ks[cur ^ 1][tid * 8]);
          GLL16(vg + (size_t)(ti + 1) * 64, &Vs[cur ^ 1][tid * 8]);
        }
        const unsigned short* Kc = &Ks[cur][0];
        const unsigned short* Vc = &Vs[cur][0];
        // swapped QK^T: sc[st] col(l15)=q, row(lg*4+r)=s_local=st*16+lg*4+r
        f32x4 sc[4];
        __builtin_amdgcn_s_setprio(1);
#pragma unroll
        for (int st = 0; st < 4; ++st) {
          const int kr = st * 16 + l15;
          const short8 kf0 = *reinterpret_cast<const short8*>(Kc + kr * 64 + SWZ(kr, lg * 8));
          const short8 kf1 = *reinterpret_cast<const short8*>(Kc + kr * 64 + SWZ(kr, 32 + lg * 8));
          f32x4 z = (f32x4){0.f, 0.f, 0.f, 0.f};
          z = __builtin_amdgcn_mfma_f32_16x16x32_bf16(kf0, qf0, z, 0, 0, 0);
          z = __builtin_amdgcn_mfma_f32_16x16x32_bf16(kf1, qf1, z, 0, 0, 0);
          sc[st] = z;
        }
        __builtin_amdgcn_s_setprio(0);
        // causal mask (wave-diagonal tiles): s = s0+st*16+lg*4+r, q = qw+l15
        if (s0 + 63 > qw) {
          const int sbase = s0 + lg * 4 - qw - l15;  // mask iff sbase+st*16+r > 0
#pragma unroll
          for (int st = 0; st < 4; ++st)
#pragma unroll
            for (int r = 0; r < 4; ++r)
              if (sbase + st * 16 + r > 0) sc[st][r] = -1e30f;
        }
        float tmax = sc[0][0];
#pragma unroll
        for (int st = 0; st < 4; ++st)
#pragma unroll
          for (int r = 0; r < 4; ++r) tmax = fmaxf(tmax, sc[st][r]);
        tmax = fmaxf(tmax, __shfl_xor(tmax, 16));
        tmax = fmaxf(tmax, __shfl_xor(tmax, 32));
        // T13 defer-max
        if (__any(tmax > mrun + 8.f)) {
          const float mn = fmaxf(mrun, tmax);
          const float c = exp2f(mrun - mn);
          mrun = mn;
          lrun *= c;
#pragma unroll
          for (int r = 0; r < 4; ++r) {
            const float cq = __shfl(c, lg * 4 + r);
            o[0][r] *= cq; o[1][r] *= cq; o[2][r] *= cq; o[3][r] *= cq;
          }
        }
        float psum = 0.f;
#pragma unroll
        for (int st = 0; st < 4; ++st) {
          const float p0 = exp2f(sc[st][0] - mrun);
          const float p1 = exp2f(sc[st][1] - mrun);
          const float p2 = exp2f(sc[st][2] - mrun);
          const float p3 = exp2f(sc[st][3] - mrun);
          psum += (p0 + p1) + (p2 + p3);
          const unsigned lo = cvt_pk_bf16(p0, p1);
          const unsigned hi = cvt_pk_bf16(p2, p3);
          const int off = l15 * 64 + SWZ(l15, st * 16 + lg * 4);
          *reinterpret_cast<uint2*>(Pw + off) = make_uint2(lo, hi);
        }
        psum += __shfl_xor(psum, 16);
        psum += __shfl_xor(psum, 32);
        lrun += psum;
        // PV: O[16q][64d] += P[16q][64s] * V[64s][64d]
        __builtin_amdgcn_s_setprio(1);
#pragma unroll
        for (int sc2 = 0; sc2 < 2; ++sc2) {
          const short8 pf =
              *reinterpret_cast<const short8*>(Pw + l15 * 64 + SWZ(l15, sc2 * 32 + lg * 8));
#pragma unroll
          for (int dt = 0; dt < 4; ++dt) {
            const int vr = dt * 16 + l15;
            const short8 vf =
                *reinterpret_cast<const short8*>(Vc + vr * 64 + SWZ(vr, sc2 * 32 + lg * 8));
            o[dt] = __builtin_amdgcn_mfma_f32_16x16x32_bf16(pf, vf, o[dt], 0, 0, 0);
          }
        }
        __builtin_amdgcn_s_setprio(0);
        __syncthreads();  // implicit vmcnt(0): next tile staged; buf[cur] free
        cur ^= 1;
      }
    }
    // unnormalized partial write: partO[sx][bh*2048 + t][d], ml for lg==0
#pragma unroll
    for (int r = 0; r < 4; ++r) {
      const int t = qw + lg * 4 + r;
      const size_t base = ((size_t)sx * 65536 + (size_t)bh * 2048 + t) * 64;
#pragma unroll
      for (int dt = 0; dt < 4; ++dt) partO[base + dt * 16 + l15] = f2bf(o[dt][r]);
    }
    if (lg == 0) partML[sx * 65536 + bh * 2048 + qw + l15] = make_float2(mrun, lrun);
  }
}

// ---------------- combine the two s-halves -> ctx bf16 ----------------------
__global__ __launch_bounds__(256) void attn_combine(
    const unsigned short* __restrict__ partO, const float2* __restrict__ partML,
    unsigned short* __restrict__ ctx) {
  const int id = blockIdx.x * 256 + threadIdx.x;
  const int R = id >> 3;
  const int d8 = (id & 7) << 3;
  const float2 ml0 = partML[R];
  const float2 ml1 = partML[65536 + R];
  const float M = fmaxf(ml0.x, ml1.x);
  const float w0 = exp2f(ml0.x - M), w1 = exp2f(ml1.x - M);
  const float inv = __builtin_amdgcn_rcpf(ml0.y * w0 + ml1.y * w1);
  const short8 a = *reinterpret_cast<const short8*>(partO + ((size_t)R * 64 + d8));
  const short8 c = *reinterpret_cast<const short8*>(partO + ((size_t)(65536 + R) * 64 + d8));
  const int bh = R >> 11, t = R & 2047;
  const int b = bh >> 4, h = bh & 15;
  short8 outv;
#pragma unroll
  for (int e = 0; e < 8; ++e)
    outv[e] = (short)f2bf((bf2f((unsigned short)a[e]) * w0 +
                           bf2f((unsigned short)c[e]) * w1) * inv);
  *reinterpret_cast<short8*>(ctx + ((size_t)(b * 2048 + t) * 1024 + h * 64 + d8)) = outv;
}

// ---------------- launch ----------------------------------------------------
extern "C" void kernel_launch(void* const* d_in, const int* in_sizes, int n_in,
                              void* d_out, int out_size, void* d_ws, size_t ws_size,
                              hipStream_t stream) {
  const float* x = (const float*)d_in[0];
  const float* w_qkv = (const float*)d_in[1];
  const float* w_out = (const float*)d_in[2];
  // cache_k/cache_v/start_pos unused: start_pos=0, cache starts zero and is not returned.
  char* ws = (char*)d_ws;
  unsigned short* xb    = (unsigned short*)(ws);                       // 8 MiB
  unsigned short* wqkvb = (unsigned short*)(ws + (8ull  << 20));       // 6 MiB
  unsigned short* woutb = (unsigned short*)(ws + (14ull << 20));       // 2 MiB
  unsigned short* partO = (unsigned short*)(ws + (16ull << 20));       // 16 MiB
  float2* partML        = (float2*)(ws + (32ull << 20));               // 1 MiB
  unsigned short* q_buf = (unsigned short*)(ws + (40ull << 20));       // 8 MiB
  unsigned short* k_buf = (unsigned short*)(ws + (48ull << 20));       // 8 MiB
  unsigned short* vt    = (unsigned short*)(ws + (56ull << 20));       // 8 MiB
  unsigned short* ctxb  = (unsigned short*)(ws + (64ull << 20));       // 8 MiB (total 72)

  cast3<<<8192, 256, 0, stream>>>(x, xb, 1048576, w_qkv, wqkvb, 786432,
                                  w_out, woutb, 262144);
  gemm_qkv<<<dim3(32, 24), 256, 0, stream>>>(xb, wqkvb, q_buf, k_buf, vt);
  attn_kernel<<<dim3(16, 32), 512, 0, stream>>>(q_buf, k_buf, vt, partO, partML);
  attn_combine<<<2048, 256, 0, stream>>>(partO, partML, ctxb);
  gemm_nt_f32<<<dim3(32, 8), 256, 0, stream>>>(ctxb, woutb, (float*)d_out, 4096, 1024, 1024);
}